// Round 3
// baseline (160.373 us; speedup 1.0000x reference)
//
#include <hip/hip_runtime.h>

// Involution2d: B=8, C=256, G=4 (Cpg=64), H=W=Ho=Wo=64, K=7, PAD=3, STRIDE=1.
// out[b, g*64+c, y, x] = sum_{kh,kw} in[b, g*64+c, y+kh-3, x+kw-3] * w[b,g,kh,kw,y,x] + bias[g*64+c]
//
// R3: channel-accumulator blocking with EXPLICIT small live set.
//  - kh loop NOT unrolled -> compiler cannot hoist all 49 weight f4 (R1 spill).
//  - per kh: w_row[7] f4 streamed (28 regs), reused across NC=8 channels.
//  - per ci: ONE 10-float LDS window (3 reads), 28 FMAs, then dead
//    (R2 kept 8 windows live -> 84-reg remat disaster, LDS-serialized 80us).
//  Live set ~= acc 32 + w_row 28 + vals 10 + addr ~20 -> ~90 regs, cap 128.

#define BLK_X 16
#define BLK_Y 16
#define NTHR (BLK_X * BLK_Y)   // 256
#define NC 8                   // channels per block
#define TILE_Y 16
#define STG_ROWS (TILE_Y + 6)  // 22
#define STG_COLS 70            // 64 + 6 halo
#define LDS_STRIDE 72          // even: keeps b128/b64 alignment; 72%32=8 rotates rows across banks
#define STG_N (NC * STG_ROWS * STG_COLS)   // 12320
#define NSTG ((STG_N + NTHR - 1) / NTHR)   // 49

__global__ __launch_bounds__(NTHR, 4)   // cap 128 VGPR -> 4 waves/EU possible
void involution_kernel(const float* __restrict__ in,
                       const float* __restrict__ w,
                       const float* __restrict__ bias,
                       float* __restrict__ out) {
    __shared__ float lds[NC * STG_ROWS * LDS_STRIDE];  // 50688 B

    const int tx = threadIdx.x;       // 0..15  (x-quad)
    const int ty = threadIdx.y;       // 0..15  (row)
    const int tid = ty * BLK_X + tx;
    const int x0 = tx * 4;
    const int Y0 = blockIdx.x * TILE_Y;
    const int y  = Y0 + ty;
    const int c0 = blockIdx.y * NC;   // channel-in-group base
    const int bz = blockIdx.z;        // b*4 + g
    const int g  = bz & 3;

    const float* inb = in + (size_t)bz * 64 * 4096 + (size_t)c0 * 4096;

    // ---- stage NC channels of the haloed input tile into LDS (once) ----
    #pragma unroll
    for (int j = 0; j < NSTG; ++j) {
        int i = tid + j * NTHR;
        if (i < STG_N) {
            int ci  = i / (STG_ROWS * STG_COLS);
            int rem = i - ci * (STG_ROWS * STG_COLS);
            int rr  = rem / STG_COLS;
            int cc  = rem - rr * STG_COLS;
            int gy  = Y0 + rr - 3;
            int gx  = cc - 3;
            float v = 0.f;
            if (gy >= 0 && gy < 64 && gx >= 0 && gx < 64)
                v = inb[ci * 4096 + gy * 64 + gx];
            lds[(ci * STG_ROWS + rr) * LDS_STRIDE + cc] = v;
        }
    }
    __syncthreads();

    float acc[NC][4];
    #pragma unroll
    for (int ci = 0; ci < NC; ++ci) {
        acc[ci][0] = 0.f; acc[ci][1] = 0.f; acc[ci][2] = 0.f; acc[ci][3] = 0.f;
    }

    const float* wb = w + (size_t)bz * 49 * 4096 + y * 64 + x0;

    #pragma unroll 1     // MUST stay a loop: unrolling lets compiler hoist 49 f4 -> spill
    for (int kh = 0; kh < 7; ++kh) {
        // stream this kh's 7 weight f4 (reused across the 8 channels, then dead)
        float4 wr[7];
        #pragma unroll
        for (int kw = 0; kw < 7; ++kw)
            wr[kw] = *(const float4*)(wb + (size_t)(kh * 7 + kw) * 4096);

        #pragma unroll
        for (int ci = 0; ci < NC; ++ci) {
            const float* lr = &lds[(ci * STG_ROWS + ty + kh) * LDS_STRIDE + x0];
            float4 a  = *(const float4*)lr;        // 16B aligned (x0, stride even)
            float4 b  = *(const float4*)(lr + 4);
            float2 c2 = *(const float2*)(lr + 8);
            float v[10] = {a.x, a.y, a.z, a.w, b.x, b.y, b.z, b.w, c2.x, c2.y};
            #pragma unroll
            for (int kw = 0; kw < 7; ++kw) {
                acc[ci][0] += v[kw + 0] * wr[kw].x;
                acc[ci][1] += v[kw + 1] * wr[kw].y;
                acc[ci][2] += v[kw + 2] * wr[kw].z;
                acc[ci][3] += v[kw + 3] * wr[kw].w;
            }
        }
    }

    // ---- epilogue: bias + coalesced float4 stores ----
    float* outb = out + (size_t)bz * 64 * 4096 + (size_t)c0 * 4096 + y * 64 + x0;
    #pragma unroll
    for (int ci = 0; ci < NC; ++ci) {
        const float bv = bias[g * 64 + c0 + ci];
        float4 o;
        o.x = acc[ci][0] + bv; o.y = acc[ci][1] + bv;
        o.z = acc[ci][2] + bv; o.w = acc[ci][3] + bv;
        *(float4*)(outb + (size_t)ci * 4096) = o;
    }
}

extern "C" void kernel_launch(void* const* d_in, const int* in_sizes, int n_in,
                              void* d_out, int out_size, void* d_ws, size_t ws_size,
                              hipStream_t stream) {
    const float* in   = (const float*)d_in[0];  // (8,256,64,64)
    const float* wgt  = (const float*)d_in[1];  // (8,4,7,7,64,64)
    const float* bias = (const float*)d_in[2];  // (256,)
    float* out = (float*)d_out;                 // (8,256,64,64)

    dim3 block(BLK_X, BLK_Y, 1);                  // 256 threads
    dim3 grid(64 / TILE_Y, 64 / NC, 32);          // (4, 8, 32) = 1024 blocks
    involution_kernel<<<grid, block, 0, stream>>>(in, wgt, bias, out);
}

// Round 4
// 134.203 us; speedup vs baseline: 1.1950x; 1.1950x over previous
//
#include <hip/hip_runtime.h>

// Involution2d: B=8, C=256, G=4 (Cpg=64), H=W=Ho=Wo=64, K=7, PAD=3, STRIDE=1.
// out[b, g*64+c, y, x] = sum_{kh,kw} in[b, g*64+c, y+kh-3, x+kw-3] * w[b,g,kh,kw,y,x] + bias[g*64+c]
//
// R4: R3's streaming structure + LDS bank-degeneracy fix + occupancy fix.
//  - ODD LDS stride (71) + SCALAR dword window reads: R3's 16B-aligned b128
//    windows put all 64 lanes in dword-banks ===0 (mod 4) (stride 72===0 mod 4,
//    base 4*tx) -> 8-way conflicts, 14 extra cyc/instr, 27us/CU of LDS serial.
//    Odd stride rotates rows across mod-4 residue classes (R1 evidence:
//    2.9 cyc/instr). Adjacent dword reads fuse into ds_read2_b32.
//  - NC=4, LDS 25KB, grid 2048 blocks, cap 128 VGPR -> 16 waves/CU to hide
//    the kh-loop's L2/L3 weight-fetch latency (R3 had only 12, and 22% meas).
//  - kh stays a real loop (unroll 1): wr[7] streamed, acc[4][4]+wr+window
//    live set ~75 regs. One barrier per block.

#define BLK_X 16
#define BLK_Y 16
#define NTHR (BLK_X * BLK_Y)   // 256
#define NC 4                   // channels per block
#define TILE_Y 16
#define STG_ROWS (TILE_Y + 6)  // 22
#define STG_COLS 70            // 64 + 6 halo
#define LDS_STRIDE 71          // ODD: spreads rows across mod-4 bank classes
#define STG_N (NC * STG_ROWS * STG_COLS)   // 6160
#define NSTG ((STG_N + NTHR - 1) / NTHR)   // 25

__global__ __launch_bounds__(NTHR, 4)   // cap 128 VGPR -> 4 waves/SIMD
void involution_kernel(const float* __restrict__ in,
                       const float* __restrict__ w,
                       const float* __restrict__ bias,
                       float* __restrict__ out) {
    __shared__ float lds[NC * STG_ROWS * LDS_STRIDE];  // 24992 B

    const int tx = threadIdx.x;       // 0..15  (x-quad)
    const int ty = threadIdx.y;       // 0..15  (row)
    const int tid = ty * BLK_X + tx;
    const int x0 = tx * 4;
    const int Y0 = blockIdx.x * TILE_Y;
    const int y  = Y0 + ty;
    const int c0 = blockIdx.y * NC;   // channel-in-group base
    const int bz = blockIdx.z;        // b*4 + g
    const int g  = bz & 3;

    const float* inb = in + (size_t)bz * 64 * 4096 + (size_t)c0 * 4096;

    // ---- stage NC channels of the haloed input tile into LDS (once) ----
    #pragma unroll
    for (int j = 0; j < NSTG; ++j) {
        int i = tid + j * NTHR;
        if (i < STG_N) {
            int ci  = i / (STG_ROWS * STG_COLS);
            int rem = i - ci * (STG_ROWS * STG_COLS);
            int rr  = rem / STG_COLS;
            int cc  = rem - rr * STG_COLS;
            int gy  = Y0 + rr - 3;
            int gx  = cc - 3;
            float v = 0.f;
            if (gy >= 0 && gy < 64 && gx >= 0 && gx < 64)
                v = inb[ci * 4096 + gy * 64 + gx];
            lds[(ci * STG_ROWS + rr) * LDS_STRIDE + cc] = v;
        }
    }
    __syncthreads();

    float acc[NC][4];
    #pragma unroll
    for (int ci = 0; ci < NC; ++ci) {
        acc[ci][0] = 0.f; acc[ci][1] = 0.f; acc[ci][2] = 0.f; acc[ci][3] = 0.f;
    }

    const float* wb = w + (size_t)bz * 49 * 4096 + y * 64 + x0;

    #pragma unroll 1     // MUST stay a loop: unrolling hoists 49 f4 -> spill (R1)
    for (int kh = 0; kh < 7; ++kh) {
        // stream this kh's 7 weight f4 (reused across NC channels, then dead)
        float4 wr[7];
        #pragma unroll
        for (int kw = 0; kw < 7; ++kw)
            wr[kw] = *(const float4*)(wb + (size_t)(kh * 7 + kw) * 4096);

        #pragma unroll
        for (int ci = 0; ci < NC; ++ci) {
            const float* lr = &lds[(ci * STG_ROWS + ty + kh) * LDS_STRIDE + x0];
            float v[10];
            #pragma unroll
            for (int j = 0; j < 10; ++j) v[j] = lr[j];   // dword reads, fuse to read2
            #pragma unroll
            for (int kw = 0; kw < 7; ++kw) {
                acc[ci][0] += v[kw + 0] * wr[kw].x;
                acc[ci][1] += v[kw + 1] * wr[kw].y;
                acc[ci][2] += v[kw + 2] * wr[kw].z;
                acc[ci][3] += v[kw + 3] * wr[kw].w;
            }
        }
    }

    // ---- epilogue: bias + coalesced float4 stores ----
    float* outb = out + (size_t)bz * 64 * 4096 + (size_t)c0 * 4096 + y * 64 + x0;
    #pragma unroll
    for (int ci = 0; ci < NC; ++ci) {
        const float bv = bias[g * 64 + c0 + ci];
        float4 o;
        o.x = acc[ci][0] + bv; o.y = acc[ci][1] + bv;
        o.z = acc[ci][2] + bv; o.w = acc[ci][3] + bv;
        *(float4*)(outb + (size_t)ci * 4096) = o;
    }
}

extern "C" void kernel_launch(void* const* d_in, const int* in_sizes, int n_in,
                              void* d_out, int out_size, void* d_ws, size_t ws_size,
                              hipStream_t stream) {
    const float* in   = (const float*)d_in[0];  // (8,256,64,64)
    const float* wgt  = (const float*)d_in[1];  // (8,4,7,7,64,64)
    const float* bias = (const float*)d_in[2];  // (256,)
    float* out = (float*)d_out;                 // (8,256,64,64)

    dim3 block(BLK_X, BLK_Y, 1);                  // 256 threads
    dim3 grid(64 / TILE_Y, 64 / NC, 32);          // (4, 16, 32) = 2048 blocks
    involution_kernel<<<grid, block, 0, stream>>>(in, wgt, bias, out);
}